// Round 4
// baseline (948.860 us; speedup 1.0000x reference)
//
#include <hip/hip_runtime.h>

#define N_NODES   50000
#define N_EDGES   640000
#define DIM       128
#define N_LAYERS  5
#define N_GRAPHS  512
#define N_CLASSES 128
#define NB_SCAN   196   // ceil(N_NODES/256)

typedef __attribute__((ext_vector_type(8))) short short8;     // 8 bf16 (4 VGPRs)
typedef __attribute__((ext_vector_type(4))) float floatx4;    // MFMA acc

__device__ inline float bfhi(unsigned u) { return __uint_as_float(u & 0xffff0000u); }
__device__ inline float bflo(unsigned u) { return __uint_as_float(u << 16); }
__device__ inline unsigned f2bf(float f) {          // round-to-nearest-even
  unsigned x = __float_as_uint(f);
  return (x + 0x7fffu + ((x >> 16) & 1u)) >> 16;
}

// ---------------- zero-init scratch accumulators (ws is poisoned 0xAA) -----
__global__ void k_zero(int* __restrict__ deg, int* __restrict__ fill,
                       float* __restrict__ pool, float* __restrict__ cnt) {
  int i = blockIdx.x * 256 + threadIdx.x;
  if (i < N_NODES) { deg[i] = 0; fill[i] = 0; }
  if (i < N_GRAPHS * DIM) pool[i] = 0.f;
  if (i < N_GRAPHS) cnt[i] = 0.f;
}

// ---------------- degree histogram over dst --------------------------------
__global__ void k_deg(const int* __restrict__ dst, int* __restrict__ deg) {
  int e = blockIdx.x * 256 + threadIdx.x;
  if (e < N_EDGES) atomicAdd(&deg[dst[e]], 1);
}

// ---------------- exclusive scan deg -> row_ptr (3 phases) -----------------
__global__ void k_scan1(const int* __restrict__ deg, int* __restrict__ bsum) {
  __shared__ int s[256];
  int t = threadIdx.x, i = blockIdx.x * 256 + t;
  s[t] = (i < N_NODES) ? deg[i] : 0;
  __syncthreads();
  for (int o = 128; o > 0; o >>= 1) {
    if (t < o) s[t] += s[t + o];
    __syncthreads();
  }
  if (t == 0) bsum[blockIdx.x] = s[0];
}

__global__ void k_scan2(int* __restrict__ bsum) {
  __shared__ int s[256];
  int t = threadIdx.x;
  s[t] = (t < NB_SCAN) ? bsum[t] : 0;
  __syncthreads();
  for (int o = 1; o < 256; o <<= 1) {
    int add = (t >= o) ? s[t - o] : 0;
    __syncthreads();
    s[t] += add;
    __syncthreads();
  }
  int ex = (t == 0) ? 0 : s[t - 1];
  if (t < NB_SCAN) bsum[t] = ex;
}

__global__ void k_scan3(const int* __restrict__ deg, const int* __restrict__ bsum,
                        int* __restrict__ row_ptr) {
  __shared__ int s[256];
  int t = threadIdx.x, i = blockIdx.x * 256 + t;
  s[t] = (i < N_NODES) ? deg[i] : 0;
  __syncthreads();
  for (int o = 1; o < 256; o <<= 1) {
    int add = (t >= o) ? s[t - o] : 0;
    __syncthreads();
    s[t] += add;
    __syncthreads();
  }
  int ex = bsum[blockIdx.x] + ((t == 0) ? 0 : s[t - 1]);
  if (i < N_NODES) row_ptr[i] = ex;
  if (blockIdx.x == 0 && t == 0) row_ptr[N_NODES] = N_EDGES;
}

// ---------------- CSR fill: col[pos] = {src, eid} (single 8B store) --------
__global__ void k_fill(const int* __restrict__ src, const int* __restrict__ dst,
                       const int* __restrict__ row_ptr, int* __restrict__ fill,
                       int2* __restrict__ col) {
  int e = blockIdx.x * 256 + threadIdx.x;
  if (e < N_EDGES) {
    int d = dst[e];
    int pos = row_ptr[d] + atomicAdd(&fill[d], 1);
    col[pos] = make_int2(src[e], e);
  }
}

// ------- weights: bf16 + transpose:  Wt[l][c][k] = W[l][k][c] --------------
__global__ void k_wconv(const float* __restrict__ Ws, const float* __restrict__ Wes,
                        unsigned short* __restrict__ Wt_s, unsigned short* __restrict__ Wt_e) {
  int idx = blockIdx.x * 256 + threadIdx.x;          // total 2*5*128*128 = 163840
  int which = idx / (N_LAYERS * DIM * DIM);
  int rem = idx - which * (N_LAYERS * DIM * DIM);
  int l = rem >> 14;            // /16384
  int c = (rem >> 7) & 127;
  int k = rem & 127;
  const float* W = which ? Wes : Ws;
  unsigned short* O = which ? Wt_e : Wt_s;
  float v = W[((size_t)l * DIM + k) * DIM + c];
  O[((size_t)l * DIM + c) * DIM + k] = (unsigned short)f2bf(v);
}

// -------- EAn = segsum(edge_attr,dst)/max(deg,1) (bf16); rdeg; h init ------
// 32 lanes per node (float4 -> 128 cols), 8 nodes per 256-thread block.
// 2-way unrolled so two edge-rows are in flight.
__global__ void k_ean_init(const int* __restrict__ row_ptr, const int2* __restrict__ col,
                           const float* __restrict__ edge_attr, const int* __restrict__ x,
                           const float* __restrict__ node_emb,
                           unsigned short* __restrict__ ean, float* __restrict__ rdeg,
                           unsigned short* __restrict__ h) {
  int sub = threadIdx.x >> 5;
  int lane = threadIdx.x & 31;
  int i = blockIdx.x * 8 + sub;
  if (i >= N_NODES) return;
  int b = row_ptr[i], e = row_ptr[i + 1];
  float4 acc0 = make_float4(0.f, 0.f, 0.f, 0.f);
  float4 acc1 = make_float4(0.f, 0.f, 0.f, 0.f);
  int p = b;
  for (; p + 1 < e; p += 2) {
    int e0 = col[p].y, e1 = col[p + 1].y;
    float4 v0 = ((const float4*)(edge_attr + (size_t)e0 * DIM))[lane];
    float4 v1 = ((const float4*)(edge_attr + (size_t)e1 * DIM))[lane];
    acc0.x += v0.x; acc0.y += v0.y; acc0.z += v0.z; acc0.w += v0.w;
    acc1.x += v1.x; acc1.y += v1.y; acc1.z += v1.z; acc1.w += v1.w;
  }
  if (p < e) {
    int e0 = col[p].y;
    float4 v0 = ((const float4*)(edge_attr + (size_t)e0 * DIM))[lane];
    acc0.x += v0.x; acc0.y += v0.y; acc0.z += v0.z; acc0.w += v0.w;
  }
  acc0.x += acc1.x; acc0.y += acc1.y; acc0.z += acc1.z; acc0.w += acc1.w;
  float r = 1.0f / (float)max(e - b, 1);
  if (lane == 0) rdeg[i] = r;
  uint2 o;
  o.x = f2bf(acc0.x * r) | (f2bf(acc0.y * r) << 16);
  o.y = f2bf(acc0.z * r) | (f2bf(acc0.w * r) << 16);
  ((uint2*)(ean + (size_t)i * DIM))[lane] = o;
  float4 hv = ((const float4*)(node_emb + (size_t)x[i] * DIM))[lane];
  uint2 ho;
  ho.x = f2bf(hv.x) | (f2bf(hv.y) << 16);
  ho.y = f2bf(hv.z) | (f2bf(hv.w) << 16);
  ((uint2*)(h + (size_t)i * DIM))[lane] = ho;
}

// ---- fused layer: gather u into LDS, then h' = relu?([u|ean]@[W;We]+b) ----
// Block: 64 rows x 128 cols, 256 threads = 4 waves.
__global__ __launch_bounds__(256) void k_layer(
    const int* __restrict__ row_ptr, const int2* __restrict__ col,
    const unsigned short* __restrict__ h, const float* __restrict__ rdeg,
    const unsigned short* __restrict__ ean,
    const unsigned short* __restrict__ W0, const unsigned short* __restrict__ W1,
    const float* __restrict__ bias, unsigned short* __restrict__ hout, int relu) {
  __shared__ unsigned short sA[64][136];   // u rows   (128 + 8 pad)
  __shared__ unsigned short sE[64][136];   // ean rows
  __shared__ unsigned short sW[128][72];   // one 64-wide K chunk of Wt
  int tid = threadIdx.x;
  int row0 = blockIdx.x * 64;

  // ---- stage ean rows: 64 rows x 16 uint4 = 1024 stores, 4 per thread ----
  #pragma unroll
  for (int q = 0; q < 4; q++) {
    int s = tid + 256 * q;
    int r = s >> 4, seg = s & 15;
    int grow = row0 + r;
    uint4 v = make_uint4(0u, 0u, 0u, 0u);
    if (grow < N_NODES) v = *(const uint4*)(ean + (size_t)grow * DIM + seg * 8);
    *(uint4*)(&sE[r][seg * 8]) = v;
  }
  // ---- gather u rows into sA: 16 lanes/node, 16 nodes in parallel --------
  {
    int sub = tid >> 4;
    int lane = tid & 15;
    for (int n = sub; n < 64; n += 16) {
      int i = row0 + n;
      uint4 o = make_uint4(0u, 0u, 0u, 0u);
      if (i < N_NODES) {
        int b = row_ptr[i], e = row_ptr[i + 1];
        float a0 = 0.f, a1 = 0.f, a2 = 0.f, a3 = 0.f;
        float a4 = 0.f, a5 = 0.f, a6 = 0.f, a7 = 0.f;
        float b0 = 0.f, b1 = 0.f, b2 = 0.f, b3 = 0.f;
        float b4 = 0.f, b5 = 0.f, b6 = 0.f, b7 = 0.f;
        int p = b;
        for (; p + 1 < e; p += 2) {
          int j0 = col[p].x, j1 = col[p + 1].x;
          uint4 v0 = *(const uint4*)(h + (size_t)j0 * DIM + lane * 8);
          uint4 v1 = *(const uint4*)(h + (size_t)j1 * DIM + lane * 8);
          a0 += bflo(v0.x); a1 += bfhi(v0.x); a2 += bflo(v0.y); a3 += bfhi(v0.y);
          a4 += bflo(v0.z); a5 += bfhi(v0.z); a6 += bflo(v0.w); a7 += bfhi(v0.w);
          b0 += bflo(v1.x); b1 += bfhi(v1.x); b2 += bflo(v1.y); b3 += bfhi(v1.y);
          b4 += bflo(v1.z); b5 += bfhi(v1.z); b6 += bflo(v1.w); b7 += bfhi(v1.w);
        }
        if (p < e) {
          int j0 = col[p].x;
          uint4 v0 = *(const uint4*)(h + (size_t)j0 * DIM + lane * 8);
          a0 += bflo(v0.x); a1 += bfhi(v0.x); a2 += bflo(v0.y); a3 += bfhi(v0.y);
          a4 += bflo(v0.z); a5 += bfhi(v0.z); a6 += bflo(v0.w); a7 += bfhi(v0.w);
        }
        a0 += b0; a1 += b1; a2 += b2; a3 += b3;
        a4 += b4; a5 += b5; a6 += b6; a7 += b7;
        float r = rdeg[i];
        uint4 hv = *(const uint4*)(h + (size_t)i * DIM + lane * 8);
        o.x = f2bf(bflo(hv.x) + a0 * r) | (f2bf(bfhi(hv.x) + a1 * r) << 16);
        o.y = f2bf(bflo(hv.y) + a2 * r) | (f2bf(bfhi(hv.y) + a3 * r) << 16);
        o.z = f2bf(bflo(hv.z) + a4 * r) | (f2bf(bfhi(hv.z) + a5 * r) << 16);
        o.w = f2bf(bflo(hv.w) + a6 * r) | (f2bf(bfhi(hv.w) + a7 * r) << 16);
      }
      *(uint4*)(&sA[n][lane * 8]) = o;
    }
  }
  __syncthreads();

  int wave = tid >> 6, lane = tid & 63;
  int quad = lane >> 4, l16 = lane & 15;
  floatx4 acc[8];
  #pragma unroll
  for (int ci = 0; ci < 8; ci++) acc[ci] = (floatx4){0.f, 0.f, 0.f, 0.f};

  #pragma unroll
  for (int m = 0; m < 2; m++) {
    const unsigned short* W = m ? W1 : W0;
    #pragma unroll
    for (int kc = 0; kc < 128; kc += 64) {
      if (m | kc) __syncthreads();       // protect previous sW reads
      #pragma unroll
      for (int q = 0; q < 4; q++) {
        int s = tid + 256 * q;
        int r = s >> 3, seg = s & 7;
        *(uint4*)(&sW[r][seg * 8]) =
            *(const uint4*)(W + (size_t)r * DIM + kc + seg * 8);
      }
      __syncthreads();
      #pragma unroll
      for (int ks = 0; ks < 64; ks += 32) {
        short8 a = m ? *(const short8*)(&sE[wave * 16 + l16][kc + ks + quad * 8])
                     : *(const short8*)(&sA[wave * 16 + l16][kc + ks + quad * 8]);
        #pragma unroll
        for (int ci = 0; ci < 8; ci++) {
          short8 b = *(const short8*)(&sW[ci * 16 + l16][ks + quad * 8]);
          acc[ci] = __builtin_amdgcn_mfma_f32_16x16x32_bf16(a, b, acc[ci], 0, 0, 0);
        }
      }
    }
  }
  // epilogue: row = row0 + wave*16 + quad*4 + r ; col = ci*16 + l16
  #pragma unroll
  for (int ci = 0; ci < 8; ci++) {
    int c = ci * 16 + l16;
    float bv = bias[c];
    #pragma unroll
    for (int r = 0; r < 4; r++) {
      int row = row0 + wave * 16 + quad * 4 + r;
      if (row < N_NODES) {
        float v = acc[ci][r] + bv;
        if (relu) v = fmaxf(v, 0.f);
        hout[(size_t)row * DIM + c] = (unsigned short)f2bf(v);
      }
    }
  }
}

// ---------------- mean-pool per graph (batch sorted: run-length) -----------
__global__ void k_pool(const unsigned short* __restrict__ h, const int* __restrict__ batch,
                       float* __restrict__ pool, float* __restrict__ cnt) {
  int t = threadIdx.x;                 // column 0..127
  int i0 = blockIdx.x * 128;
  int iend = min(i0 + 128, N_NODES);
  float acc = 0.f;
  int cur = -1, run = 0;
  for (int i = i0; i < iend; i++) {
    int g = batch[i];
    if (g != cur) {
      if (cur >= 0) {
        atomicAdd(&pool[(size_t)cur * DIM + t], acc);
        if (t == 0) atomicAdd(&cnt[cur], (float)run);
      }
      acc = 0.f; run = 0; cur = g;
    }
    acc += __uint_as_float(((unsigned)h[(size_t)i * DIM + t]) << 16);
    run++;
  }
  if (cur >= 0) {
    atomicAdd(&pool[(size_t)cur * DIM + t], acc);
    if (t == 0) atomicAdd(&cnt[cur], (float)run);
  }
}

// ---------------- out = (pool/cnt) @ Wp + bp -------------------------------
__global__ void k_out(const float* __restrict__ pool, const float* __restrict__ cnt,
                      const float* __restrict__ Wp, const float* __restrict__ bp,
                      float* __restrict__ out) {
  __shared__ float sp[DIM];
  int g = blockIdx.x, t = threadIdx.x;
  sp[t] = pool[(size_t)g * DIM + t];
  __syncthreads();
  float r = 1.0f / fmaxf(cnt[g], 1.0f);
  float acc = 0.f;
  for (int k = 0; k < DIM; k++) acc += sp[k] * Wp[(size_t)k * N_CLASSES + t];
  out[(size_t)g * N_CLASSES + t] = acc * r + bp[t];
}

extern "C" void kernel_launch(void* const* d_in, const int* in_sizes, int n_in,
                              void* d_out, int out_size, void* d_ws, size_t ws_size,
                              hipStream_t stream) {
  (void)in_sizes; (void)n_in; (void)out_size; (void)ws_size;
  const int*   x          = (const int*)d_in[0];
  const int*   edge_index = (const int*)d_in[1];
  const float* edge_attr  = (const float*)d_in[2];
  const int*   batch      = (const int*)d_in[3];
  const float* node_emb   = (const float*)d_in[4];
  const float* Ws         = (const float*)d_in[5];
  const float* bs         = (const float*)d_in[6];
  const float* Wes        = (const float*)d_in[7];
  const float* Wp         = (const float*)d_in[8];
  const float* bp         = (const float*)d_in[9];
  float* out = (float*)d_out;
  const int* src = edge_index;
  const int* dst = edge_index + N_EDGES;

  char* p = (char*)d_ws;
  auto alloc = [&](size_t bytes) {
    void* q = (void*)p;
    p += (bytes + 255) & ~(size_t)255;
    return q;
  };
  unsigned short* h    = (unsigned short*)alloc((size_t)N_NODES * DIM * 2);
  unsigned short* hb   = (unsigned short*)alloc((size_t)N_NODES * DIM * 2);
  unsigned short* ean  = (unsigned short*)alloc((size_t)N_NODES * DIM * 2);
  unsigned short* Wt_s = (unsigned short*)alloc((size_t)N_LAYERS * DIM * DIM * 2);
  unsigned short* Wt_e = (unsigned short*)alloc((size_t)N_LAYERS * DIM * DIM * 2);
  int*   deg     = (int*)  alloc((size_t)N_NODES * 4);
  float* rdeg    = (float*)alloc((size_t)N_NODES * 4);
  int*   row_ptr = (int*)  alloc((size_t)(N_NODES + 64) * 4);
  int*   fill    = (int*)  alloc((size_t)N_NODES * 4);
  int2*  col     = (int2*) alloc((size_t)N_EDGES * 8);
  float* pool    = (float*)alloc((size_t)N_GRAPHS * DIM * 4);
  float* cnt     = (float*)alloc((size_t)N_GRAPHS * 4);
  int*   bsum    = (int*)  alloc(256 * 4);

  k_zero<<<256, 256, 0, stream>>>(deg, fill, pool, cnt);
  k_deg<<<(N_EDGES + 255) / 256, 256, 0, stream>>>(dst, deg);
  k_scan1<<<NB_SCAN, 256, 0, stream>>>(deg, bsum);
  k_scan2<<<1, 256, 0, stream>>>(bsum);
  k_scan3<<<NB_SCAN, 256, 0, stream>>>(deg, bsum, row_ptr);
  k_fill<<<(N_EDGES + 255) / 256, 256, 0, stream>>>(src, dst, row_ptr, fill, col);
  k_wconv<<<(2 * N_LAYERS * DIM * DIM) / 256, 256, 0, stream>>>(Ws, Wes, Wt_s, Wt_e);
  k_ean_init<<<(N_NODES + 7) / 8, 256, 0, stream>>>(row_ptr, col, edge_attr, x,
                                                    node_emb, ean, rdeg, h);
  unsigned short* cur = h;
  unsigned short* nxt = hb;
  for (int l = 0; l < N_LAYERS; l++) {
    k_layer<<<(N_NODES + 63) / 64, 256, 0, stream>>>(
        row_ptr, col, cur, rdeg, ean,
        Wt_s + (size_t)l * DIM * DIM, Wt_e + (size_t)l * DIM * DIM,
        bs + (size_t)l * DIM, nxt, (l < N_LAYERS - 1) ? 1 : 0);
    unsigned short* t = cur; cur = nxt; nxt = t;
  }
  k_pool<<<(N_NODES + 127) / 128, 128, 0, stream>>>(cur, batch, pool, cnt);
  k_out<<<N_GRAPHS, N_CLASSES, 0, stream>>>(pool, cnt, Wp, bp, out);
}